// Round 3
// baseline (141.948 us; speedup 1.0000x reference)
//
#include <hip/hip_runtime.h>
#include <hip/hip_bf16.h>
#include <stdint.h>

#define BATCH 16384
#define NF 768
#define FT 1024
#define PAD_M 4
#define DUMMY NF            // index of the zeroed row in Wq
#define QMAX 1820.0f        // 18 slots/acc * 1820 = 32760 < 32767

typedef short s16x2 __attribute__((ext_vector_type(2)));

// ---------------- prep 1: absmax(W_ft) -> ws_absmax (uint bits) -------------
__global__ __launch_bounds__(256) void prep_absmax(const float* __restrict__ W,
                                                   unsigned int* __restrict__ amax) {
    int i = (blockIdx.x * 256 + threadIdx.x) * 4;
    float4 v = *(const float4*)(W + i);
    float m = fmaxf(fmaxf(fabsf(v.x), fabsf(v.y)), fmaxf(fabsf(v.z), fabsf(v.w)));
    #pragma unroll
    for (int s = 32; s > 0; s >>= 1) m = fmaxf(m, __shfl_down(m, s, 64));
    if ((threadIdx.x & 63) == 0)
        atomicMax(amax, __float_as_uint(m));   // floats >= 0: uint order == float order
}

// ---- prep 2: W_ft [FT,NF] f32 -> Wq [(NF+1),FT] i16 (transposed, scaled) ---
__global__ __launch_bounds__(256) void prep_wq(const float* __restrict__ W_ft,
                                               const unsigned int* __restrict__ amax,
                                               short* __restrict__ Wq) {
    int n = blockIdx.x * 256 + threadIdx.x;
    if (n >= (NF + 1) * FT) return;
    const float s = QMAX / __uint_as_float(*amax);
    int o = n & (FT - 1);
    int f = n >> 10;
    float w = (f < NF) ? W_ft[(size_t)o * NF + f] : 0.0f;
    Wq[n] = (short)(int)rintf(w * s);
}

// -------- fused sparse FT + SCReLU + output layer + sigmoid -----------------
// One block per batch row. Threads 0-127: stm outputs (8 each); 128-255: nstm.
__global__ __launch_bounds__(256) void nnue_fwd(
    const float* __restrict__ bstm, const float* __restrict__ bnstm,
    const short* __restrict__ Wq, const unsigned int* __restrict__ amax,
    const float* __restrict__ b_ft, const float* __restrict__ W_out,
    const float* __restrict__ b_out, float* __restrict__ out)
{
    const int b = blockIdx.x;
    const int t = threadIdx.x;
    const int wave = t >> 6;
    const int lane = t & 63;

    __shared__ int fidx[2][NF + PAD_M];
    __shared__ int cnt[2];
    __shared__ float red[4];

    // Phase 1: wave 0 compacts stm nonzero indices, wave 1 nstm (boards binary).
    if (wave < 2) {
        const float* board = (wave == 0 ? bstm : bnstm) + (size_t)b * NF;
        int base = 0;
        #pragma unroll
        for (int c = 0; c < 3; ++c) {
            const float4 v = ((const float4*)board)[lane * 3 + c];
            const float arr[4] = {v.x, v.y, v.z, v.w};
            #pragma unroll
            for (int j = 0; j < 4; ++j) {
                const bool nz = (arr[j] != 0.0f);
                const uint64_t m = __ballot(nz);
                if (nz) {
                    int pos = base + __popcll(m & ((1ull << lane) - 1ull));
                    fidx[wave][pos] = lane * 12 + c * 4 + j;
                }
                base += __popcll(m);
            }
        }
        const int padded = (base + PAD_M - 1) & ~(PAD_M - 1);
        if (lane < padded - base) fidx[wave][base + lane] = DUMMY;
        if (lane == 0) cnt[wave] = padded;
    }
    __syncthreads();

    // Phase 2: packed-i16 accumulate of active rows. 1 v_pk_add_i16 per u32.
    // 4 rotating accumulators per column (one per unroll slot): per-slot row
    // count <= 18, 18*1820 = 32760 < 32767 -> no overflow.
    const int p = t >> 7;
    const int obase = (t & 127) * 8;
    const short* wrow = Wq + obase;
    s16x2 acc[4][4] = {};   // [column][slot]
    const int n = cnt[p];
    for (int i0 = 0; i0 < n; i0 += 4) {
        const int4 fi = *(const int4*)&fidx[p][i0];
        const int f0 = __builtin_amdgcn_readfirstlane(fi.x);
        const int f1 = __builtin_amdgcn_readfirstlane(fi.y);
        const int f2 = __builtin_amdgcn_readfirstlane(fi.z);
        const int f3 = __builtin_amdgcn_readfirstlane(fi.w);
        const uint4 w0 = *(const uint4*)(wrow + (size_t)f0 * FT);
        const uint4 w1 = *(const uint4*)(wrow + (size_t)f1 * FT);
        const uint4 w2 = *(const uint4*)(wrow + (size_t)f2 * FT);
        const uint4 w3 = *(const uint4*)(wrow + (size_t)f3 * FT);
        const uint32_t wc[4][4] = {{w0.x, w0.y, w0.z, w0.w},
                                   {w1.x, w1.y, w1.z, w1.w},
                                   {w2.x, w2.y, w2.z, w2.w},
                                   {w3.x, w3.y, w3.z, w3.w}};
        #pragma unroll
        for (int r = 0; r < 4; ++r)
            #pragma unroll
            for (int c = 0; c < 4; ++c) {
                s16x2 wv;
                __builtin_memcpy(&wv, &wc[r][c], 4);
                acc[c][r] += wv;
            }
    }

    // Phase 3: dequant + bias + SCReLU + dot with W_out slice.
    const float invs = __uint_as_float(*amax) / QMAX;
    const float4 bias0 = *(const float4*)(b_ft + obase);
    const float4 bias1 = *(const float4*)(b_ft + obase + 4);
    const float4 wo0 = *(const float4*)(W_out + p * FT + obase);
    const float4 wo1 = *(const float4*)(W_out + p * FT + obase + 4);
    const float bb[8] = {bias0.x, bias0.y, bias0.z, bias0.w,
                         bias1.x, bias1.y, bias1.z, bias1.w};
    const float wo[8] = {wo0.x, wo0.y, wo0.z, wo0.w,
                         wo1.x, wo1.y, wo1.z, wo1.w};
    float partial = 0.0f;
    #pragma unroll
    for (int c = 0; c < 4; ++c) {
        const int e0 = (int)acc[c][0].x + (int)acc[c][1].x
                     + (int)acc[c][2].x + (int)acc[c][3].x;
        const int e1 = (int)acc[c][0].y + (int)acc[c][1].y
                     + (int)acc[c][2].y + (int)acc[c][3].y;
        float h0 = fmaf((float)e0, invs, bb[2 * c]);
        float h1 = fmaf((float)e1, invs, bb[2 * c + 1]);
        h0 = fminf(fmaxf(h0, 0.0f), 1.0f);
        h1 = fminf(fmaxf(h1, 0.0f), 1.0f);
        partial = fmaf(h0 * h0, wo[2 * c], partial);
        partial = fmaf(h1 * h1, wo[2 * c + 1], partial);
    }

    #pragma unroll
    for (int s = 32; s > 0; s >>= 1) partial += __shfl_down(partial, s, 64);
    if (lane == 0) red[wave] = partial;
    __syncthreads();
    if (t == 0) {
        float x = red[0] + red[1] + red[2] + red[3] + b_out[0];
        out[b] = 1.0f / (1.0f + expf(-x));
    }
}

extern "C" void kernel_launch(void* const* d_in, const int* in_sizes, int n_in,
                              void* d_out, int out_size, void* d_ws, size_t ws_size,
                              hipStream_t stream) {
    const float* board_stm  = (const float*)d_in[0];
    const float* board_nstm = (const float*)d_in[1];
    const float* W_ft       = (const float*)d_in[2];
    const float* b_ft       = (const float*)d_in[3];
    const float* W_out      = (const float*)d_in[4];
    const float* b_out      = (const float*)d_in[5];
    float* out = (float*)d_out;

    short* Wq = (short*)d_ws;                                // (NF+1)*FT i16
    unsigned int* amax = (unsigned int*)((char*)d_ws + (size_t)(NF + 1) * FT * 2);

    hipMemsetAsync(amax, 0, 4, stream);
    prep_absmax<<<NF * NF * FT / (256 * 4 * NF), 256, 0, stream>>>(W_ft, amax);
    prep_wq<<<((NF + 1) * FT + 255) / 256, 256, 0, stream>>>(W_ft, amax, Wq);
    nnue_fwd<<<BATCH, 256, 0, stream>>>(board_stm, board_nstm, Wq, amax,
                                        b_ft, W_out, b_out, out);
}

// Round 4
// 80.328 us; speedup vs baseline: 1.7671x; 1.7671x over previous
//
#include <hip/hip_runtime.h>
#include <stdint.h>

#define BATCH 16384
#define NF 768
#define FT 1024
#define DUMMY NF
#define PAD_M 4

// ---- prep: W_ft [FT,NF] f32 -> Wq [(NF+1),FT] biased-u8 (transposed) -------
// One block per output column o. Reads row o of W_ft (768 contiguous f32),
// computes absmax_o, quantizes with s_o = 127/absmax_o, stores byte = q+128.
// Also writes invs[o] = absmax_o/127 and the zero dummy row (byte 128).
__global__ __launch_bounds__(192) void prep_wq(const float* __restrict__ W_ft,
                                               unsigned char* __restrict__ Wq,
                                               float* __restrict__ invs) {
    const int o = blockIdx.x;
    const int t = threadIdx.x;
    __shared__ float smax[3];
    __shared__ float sscale;
    const float4 v = *(const float4*)(W_ft + (size_t)o * NF + t * 4);
    float m = fmaxf(fmaxf(fabsf(v.x), fabsf(v.y)), fmaxf(fabsf(v.z), fabsf(v.w)));
    #pragma unroll
    for (int s = 32; s > 0; s >>= 1) m = fmaxf(m, __shfl_down(m, s, 64));
    if ((t & 63) == 0) smax[t >> 6] = m;
    __syncthreads();
    if (t == 0) {
        const float am = fmaxf(fmaxf(smax[0], smax[1]), smax[2]);
        sscale = 127.0f / am;
        invs[o] = am / 127.0f;
        Wq[(size_t)DUMMY * FT + o] = 128;
    }
    __syncthreads();
    const float s = sscale;
    const float arr[4] = {v.x, v.y, v.z, v.w};
    #pragma unroll
    for (int j = 0; j < 4; ++j) {
        const int q = (int)rintf(arr[j] * s);
        Wq[(size_t)(t * 4 + j) * FT + o] = (unsigned char)(q + 128);
    }
}

// ---- fused sparse FT + SCReLU + output layer + sigmoid ---------------------
// 2 batch rows per block; wave wv handles (row = 2*blk + wv/2, persp = wv&1).
// Each lane owns 16 consecutive outputs: one dwordx4 u8 load per feature.
__global__ __launch_bounds__(256) void nnue_fwd(
    const float* __restrict__ bstm, const float* __restrict__ bnstm,
    const unsigned char* __restrict__ Wq, const float* __restrict__ invs,
    const float* __restrict__ b_ft, const float* __restrict__ W_out,
    const float* __restrict__ b_out, float* __restrict__ out)
{
    const int t = threadIdx.x;
    const int wv = t >> 6;
    const int lane = t & 63;
    const int row = blockIdx.x * 2 + (wv >> 1);
    const int p = wv & 1;

    __shared__ int fidx[4][NF + PAD_M];
    __shared__ float red[4];

    // Phase 1: per-wave ballot compaction of this board's nonzero indices.
    const float* board = (p ? bnstm : bstm) + (size_t)row * NF;
    int base = 0;
    #pragma unroll
    for (int c = 0; c < 3; ++c) {
        const float4 v = *(const float4*)(board + lane * 12 + c * 4);
        const float arr[4] = {v.x, v.y, v.z, v.w};
        #pragma unroll
        for (int j = 0; j < 4; ++j) {
            const bool nz = (arr[j] != 0.0f);
            const uint64_t m = __ballot(nz);
            if (nz) {
                const int pos = base + __popcll(m & ((1ull << lane) - 1ull));
                fidx[wv][pos] = lane * 12 + c * 4 + j;
            }
            base += __popcll(m);   // wave-uniform
        }
    }
    const int padded = (base + PAD_M - 1) & ~(PAD_M - 1);
    if (lane < padded - base) fidx[wv][base + lane] = DUMMY;
    // padded is wave-uniform in registers; fidx[wv] is wave-private: no barrier.

    // Phase 2: u8 gather + split-u16 accumulate. accE[k] holds outputs
    // (4k, 4k+2) as u16 lanes; accO[k] holds (4k+1, 4k+3). No overflow:
    // max 72 active * 255 = 18360 < 65536, so plain u32 adds are exact.
    uint32_t accE[4] = {0, 0, 0, 0}, accO[4] = {0, 0, 0, 0};
    const unsigned char* wbase = Wq + lane * 16;
    for (int i0 = 0; i0 < padded; i0 += 4) {
        const int4 fi = *(const int4*)&fidx[wv][i0];   // broadcast LDS read
        const int f0 = __builtin_amdgcn_readfirstlane(fi.x);
        const int f1 = __builtin_amdgcn_readfirstlane(fi.y);
        const int f2 = __builtin_amdgcn_readfirstlane(fi.z);
        const int f3 = __builtin_amdgcn_readfirstlane(fi.w);
        const uint4 w0 = *(const uint4*)(wbase + (size_t)f0 * FT);
        const uint4 w1 = *(const uint4*)(wbase + (size_t)f1 * FT);
        const uint4 w2 = *(const uint4*)(wbase + (size_t)f2 * FT);
        const uint4 w3 = *(const uint4*)(wbase + (size_t)f3 * FT);
        const uint32_t wc[4][4] = {{w0.x, w0.y, w0.z, w0.w},
                                   {w1.x, w1.y, w1.z, w1.w},
                                   {w2.x, w2.y, w2.z, w2.w},
                                   {w3.x, w3.y, w3.z, w3.w}};
        #pragma unroll
        for (int r = 0; r < 4; ++r)
            #pragma unroll
            for (int k = 0; k < 4; ++k) {
                accE[k] += wc[r][k] & 0x00FF00FFu;
                accO[k] += (wc[r][k] >> 8) & 0x00FF00FFu;
            }
    }

    // Phase 3: dequant (undo +128 bias via -128*padded) + bias + SCReLU +
    // dot with W_out slice.
    const int obase = lane * 16;
    const float fcorr = 128.0f * (float)padded;
    float partial = 0.0f;
    #pragma unroll
    for (int k = 0; k < 4; ++k) {
        const int o0 = obase + 4 * k;
        const float4 iv = *(const float4*)(invs + o0);
        const float4 bv = *(const float4*)(b_ft + o0);
        const float4 wo = *(const float4*)(W_out + p * FT + o0);
        const float sums[4] = {(float)(int)(accE[k] & 0xFFFFu),
                               (float)(int)(accO[k] & 0xFFFFu),
                               (float)(int)(accE[k] >> 16),
                               (float)(int)(accO[k] >> 16)};
        const float ivv[4] = {iv.x, iv.y, iv.z, iv.w};
        const float bvv[4] = {bv.x, bv.y, bv.z, bv.w};
        const float wov[4] = {wo.x, wo.y, wo.z, wo.w};
        #pragma unroll
        for (int j = 0; j < 4; ++j) {
            float h = fmaf(sums[j] - fcorr, ivv[j], bvv[j]);
            h = fminf(fmaxf(h, 0.0f), 1.0f);
            partial = fmaf(h * h, wov[j], partial);
        }
    }

    #pragma unroll
    for (int s = 32; s > 0; s >>= 1) partial += __shfl_down(partial, s, 64);
    if (lane == 0) red[wv] = partial;
    __syncthreads();
    if ((t & 127) == 0) {
        const int r = wv >> 1;
        const float x = red[2 * r] + red[2 * r + 1] + b_out[0];
        out[blockIdx.x * 2 + r] = 1.0f / (1.0f + expf(-x));
    }
}

extern "C" void kernel_launch(void* const* d_in, const int* in_sizes, int n_in,
                              void* d_out, int out_size, void* d_ws, size_t ws_size,
                              hipStream_t stream) {
    const float* board_stm  = (const float*)d_in[0];
    const float* board_nstm = (const float*)d_in[1];
    const float* W_ft       = (const float*)d_in[2];
    const float* b_ft       = (const float*)d_in[3];
    const float* W_out      = (const float*)d_in[4];
    const float* b_out      = (const float*)d_in[5];
    float* out = (float*)d_out;

    unsigned char* Wq = (unsigned char*)d_ws;            // (NF+1)*FT = 787456 B
    float* invs = (float*)((char*)d_ws + (size_t)(NF + 1) * FT);  // 4 KB

    prep_wq<<<FT, 192, 0, stream>>>(W_ft, Wq, invs);
    nnue_fwd<<<BATCH / 2, 256, 0, stream>>>(board_stm, board_nstm, Wq, invs,
                                            b_ft, W_out, b_out, out);
}

// Round 5
// 76.213 us; speedup vs baseline: 1.8625x; 1.0540x over previous
//
#include <hip/hip_runtime.h>
#include <stdint.h>

#define BATCH 16384
#define NF 768
#define FT 1024
#define RB 32               // batch rows per block
#define GR (2 * RB)         // GEMM rows per block (stm rows 0-31, nstm 32-63)
#define ALD 784             // A-LDS row stride bytes (768 + 16 pad)
#define NW 8
#define THREADS 512

typedef int i32x4 __attribute__((ext_vector_type(4)));

// ---- prep: W_ft [FT][NF] f32 -> Wq [FT][NF] i8 (per-row scale 127/absmax) --
__global__ __launch_bounds__(192) void prep_wq(const float* __restrict__ W_ft,
                                               char* __restrict__ Wq,
                                               float* __restrict__ invs) {
    const int o = blockIdx.x;
    const int t = threadIdx.x;
    __shared__ float smax[3];
    __shared__ float sscale;
    const float4 v = *(const float4*)(W_ft + (size_t)o * NF + t * 4);
    float m = fmaxf(fmaxf(fabsf(v.x), fabsf(v.y)), fmaxf(fabsf(v.z), fabsf(v.w)));
    #pragma unroll
    for (int s = 32; s > 0; s >>= 1) m = fmaxf(m, __shfl_down(m, s, 64));
    if ((t & 63) == 0) smax[t >> 6] = m;
    __syncthreads();
    if (t == 0) {
        const float am = fmaxf(fmaxf(smax[0], smax[1]), smax[2]);
        sscale = 127.0f / am;
        invs[o] = am / 127.0f;
    }
    __syncthreads();
    const float s = sscale;
    const float arr[4] = {v.x, v.y, v.z, v.w};
    uint32_t pk = 0;
    #pragma unroll
    for (int j = 0; j < 4; ++j) {
        const int q = (int)rintf(arr[j] * s);
        pk |= ((uint32_t)(unsigned char)(char)q) << (8 * j);
    }
    *(uint32_t*)(Wq + (size_t)o * NF + t * 4) = pk;
}

// ---- fused dense i8-MFMA FT + SCReLU + output layer + sigmoid --------------
// Block: 32 batch rows, both perspectives = 64 GEMM rows x 1024 cols.
// Wave w owns cols [128w, 128w+128). acc[r][c]: row-frag r (16 rows), col-frag c.
__global__ __launch_bounds__(THREADS, 2) void nnue_mfma(
    const float* __restrict__ bstm, const float* __restrict__ bnstm,
    const char* __restrict__ Wq, const float* __restrict__ invs,
    const float* __restrict__ b_ft, const float* __restrict__ W_out,
    const float* __restrict__ b_out, float* __restrict__ out)
{
    __shared__ __align__(16) char Albs[GR * ALD];   // 50176 B
    __shared__ float red[GR][NW];                   // 2048 B

    const int t = threadIdx.x;
    const int w = t >> 6;
    const int l = t & 63;
    const int b0 = blockIdx.x * RB;

    // Phase 1: stage boards -> i8 {0,1} in LDS. 64 rows x 192 float4.
    #pragma unroll
    for (int it = 0; it < 24; ++it) {
        const int g = it * THREADS + t;
        const int row = g / 192;
        const int c4 = g - row * 192;
        const float* src = (row < RB) ? (bstm + (size_t)(b0 + row) * NF)
                                      : (bnstm + (size_t)(b0 + row - RB) * NF);
        const float4 v = *(const float4*)(src + c4 * 4);
        const uint32_t pk = (uint32_t)(v.x != 0.0f)
                          | ((uint32_t)(v.y != 0.0f) << 8)
                          | ((uint32_t)(v.z != 0.0f) << 16)
                          | ((uint32_t)(v.w != 0.0f) << 24);
        *(uint32_t*)(Albs + row * ALD + c4 * 4) = pk;
    }
    __syncthreads();

    // Phase 2: K-loop. A: lane holds A[row=l&15][k=(l>>4)*16+j] from LDS.
    // B: lane holds B[k=(l>>4)*16+j][col=l&15] -> 16 contiguous bytes of Wq[col][.].
    i32x4 acc[4][8] = {};
    const int cl = l & 15;
    const int q = l >> 4;
    const char* bptr = Wq + (size_t)(w * 128 + cl) * NF + q * 16;
    const int aoff = cl * ALD + q * 16;

    #pragma unroll 2
    for (int ks = 0; ks < 12; ++ks) {
        i32x4 bfrag[8];
        #pragma unroll
        for (int c = 0; c < 8; ++c)
            bfrag[c] = *(const i32x4*)(bptr + c * 16 * NF + ks * 64);
        i32x4 afrag[4];
        #pragma unroll
        for (int r = 0; r < 4; ++r)
            afrag[r] = *(const i32x4*)(Albs + aoff + r * 16 * ALD + ks * 64);
        #pragma unroll
        for (int r = 0; r < 4; ++r)
            #pragma unroll
            for (int c = 0; c < 8; ++c)
                acc[r][c] = __builtin_amdgcn_mfma_i32_16x16x64_i8(
                    afrag[r], bfrag[c], acc[r][c], 0, 0, 0);
    }

    // Phase 3: epilogue. C/D: lane l holds col=l&15, row=(l>>4)*4+j (m89).
    float ps[4][4] = {};   // [row-frag][j] partial over this lane's 8 cols
    #pragma unroll
    for (int c = 0; c < 8; ++c) {
        const int col = w * 128 + c * 16 + cl;
        const float iv = invs[col];
        const float bf = b_ft[col];
        const float wo0 = W_out[col];
        const float wo1 = W_out[FT + col];
        #pragma unroll
        for (int r = 0; r < 4; ++r) {
            const float wo = (r < 2) ? wo0 : wo1;   // rows 0-31 stm, 32-63 nstm
            #pragma unroll
            for (int j = 0; j < 4; ++j) {
                float h = fmaf((float)acc[r][c][j], iv, bf);
                h = fminf(fmaxf(h, 0.0f), 1.0f);
                ps[r][j] = fmaf(h * h, wo, ps[r][j]);
            }
        }
    }
    // reduce across the 16 lanes sharing a row (xor bits 0-3)
    #pragma unroll
    for (int r = 0; r < 4; ++r)
        #pragma unroll
        for (int j = 0; j < 4; ++j) {
            float v = ps[r][j];
            v += __shfl_xor(v, 1, 64);
            v += __shfl_xor(v, 2, 64);
            v += __shfl_xor(v, 4, 64);
            v += __shfl_xor(v, 8, 64);
            if (cl == 0) red[16 * r + 4 * q + j][w] = v;
        }
    __syncthreads();

    // Phase 4: per batch row, sum stm(g=t) + nstm(g=32+t) over 8 waves.
    if (t < RB) {
        float x = b_out[0];
        #pragma unroll
        for (int w2 = 0; w2 < NW; ++w2)
            x += red[t][w2] + red[RB + t][w2];
        out[b0 + t] = 1.0f / (1.0f + expf(-x));
    }
}

extern "C" void kernel_launch(void* const* d_in, const int* in_sizes, int n_in,
                              void* d_out, int out_size, void* d_ws, size_t ws_size,
                              hipStream_t stream) {
    const float* board_stm  = (const float*)d_in[0];
    const float* board_nstm = (const float*)d_in[1];
    const float* W_ft       = (const float*)d_in[2];
    const float* b_ft       = (const float*)d_in[3];
    const float* W_out      = (const float*)d_in[4];
    const float* b_out      = (const float*)d_in[5];
    float* out = (float*)d_out;

    char* Wq = (char*)d_ws;                               // FT*NF i8 = 768 KB
    float* invs = (float*)((char*)d_ws + (size_t)FT * NF); // 4 KB

    prep_wq<<<FT, 192, 0, stream>>>(W_ft, Wq, invs);
    nnue_mfma<<<BATCH / RB, THREADS, 0, stream>>>(board_stm, board_nstm, Wq, invs,
                                                  b_ft, W_out, b_out, out);
}

// Round 6
// 75.003 us; speedup vs baseline: 1.8926x; 1.0161x over previous
//
#include <hip/hip_runtime.h>
#include <stdint.h>

#define BATCH 16384
#define NF 768
#define FT 1024
#define RB 32               // batch rows per block
#define GR (2 * RB)         // GEMM rows per block (stm 0-31, nstm 32-63)
#define THREADS 1024
#define NW 16
#define ALD 80              // A-chunk row stride bytes (64 + 16 pad)
#define NKS 12              // 768 / 64 K-steps

typedef int i32x4 __attribute__((ext_vector_type(4)));

// ---- prep: W_ft [FT][NF] f32 -> Wq [FT][NF] i8 (per-row scale 127/absmax) --
__global__ __launch_bounds__(192) void prep_wq(const float* __restrict__ W_ft,
                                               char* __restrict__ Wq,
                                               float* __restrict__ invs) {
    const int o = blockIdx.x;
    const int t = threadIdx.x;
    __shared__ float smax[3];
    __shared__ float sscale;
    const float4 v = *(const float4*)(W_ft + (size_t)o * NF + t * 4);
    float m = fmaxf(fmaxf(fabsf(v.x), fabsf(v.y)), fmaxf(fabsf(v.z), fabsf(v.w)));
    #pragma unroll
    for (int s = 32; s > 0; s >>= 1) m = fmaxf(m, __shfl_down(m, s, 64));
    if ((t & 63) == 0) smax[t >> 6] = m;
    __syncthreads();
    if (t == 0) {
        const float am = fmaxf(fmaxf(smax[0], smax[1]), smax[2]);
        sscale = 127.0f / am;
        invs[o] = am / 127.0f;
    }
    __syncthreads();
    const float s = sscale;
    const float arr[4] = {v.x, v.y, v.z, v.w};
    uint32_t pk = 0;
    #pragma unroll
    for (int j = 0; j < 4; ++j) {
        const int q = (int)rintf(arr[j] * s);
        pk |= ((uint32_t)(unsigned char)(char)q) << (8 * j);
    }
    *(uint32_t*)(Wq + (size_t)o * NF + t * 4) = pk;
}

__device__ __forceinline__ uint32_t pack01(float4 v) {
    return (uint32_t)(v.x != 0.0f) | ((uint32_t)(v.y != 0.0f) << 8)
         | ((uint32_t)(v.z != 0.0f) << 16) | ((uint32_t)(v.w != 0.0f) << 24);
}

// ---- fused dense i8-MFMA FT + SCReLU + output layer + sigmoid --------------
// 16 waves; wave w owns cols [64w, 64w+64) x all 64 GEMM rows. A staged in
// 64-feature chunks, double-buffered, one step ahead of the MFMA K-loop.
__global__ __launch_bounds__(THREADS, 4) void nnue_mfma(
    const float* __restrict__ bstm, const float* __restrict__ bnstm,
    const char* __restrict__ Wq, const float* __restrict__ invs,
    const float* __restrict__ b_ft, const float* __restrict__ W_out,
    const float* __restrict__ b_out, float* __restrict__ out)
{
    __shared__ __align__(16) char Abuf[2][GR * ALD];   // 2 x 5120 B
    __shared__ float red[GR][NW];                      // 4096 B

    const int t = threadIdx.x;
    const int w = t >> 6;
    const int l = t & 63;
    const int b0 = blockIdx.x * RB;

    // Staging role: thread handles (row = t>>4, features sseg*4..+3 of chunk).
    const int srow = t >> 4;
    const int sseg = t & 15;
    const float* sbase = ((srow < RB) ? (bstm + (size_t)(b0 + srow) * NF)
                                      : (bnstm + (size_t)(b0 + srow - RB) * NF))
                         + sseg * 4;
    const int swr = srow * ALD + sseg * 4;

    // Prologue: stage chunk 0.
    *(uint32_t*)(&Abuf[0][swr]) = pack01(*(const float4*)sbase);
    __syncthreads();

    const int cl = l & 15;
    const int q = l >> 4;
    const char* bptr = Wq + (size_t)(w * 64 + cl) * NF + q * 16;
    const int aoff = cl * ALD + q * 16;

    i32x4 acc[4][4] = {};
    #pragma unroll 2
    for (int ks = 0; ks < NKS; ++ks) {
        const int cur = ks & 1;
        // issue next-chunk board load early (hides HBM latency under MFMA)
        float4 nv;
        if (ks < NKS - 1) nv = *(const float4*)(sbase + (ks + 1) * 64);
        // B fragments: 4 x 16B from L2-resident Wq
        i32x4 bfrag[4];
        #pragma unroll
        for (int c = 0; c < 4; ++c)
            bfrag[c] = *(const i32x4*)(bptr + (size_t)c * 16 * NF + ks * 64);
        // A fragments from current LDS chunk
        i32x4 afrag[4];
        #pragma unroll
        for (int r = 0; r < 4; ++r)
            afrag[r] = *(const i32x4*)(&Abuf[cur][aoff + r * 16 * ALD]);
        #pragma unroll
        for (int r = 0; r < 4; ++r)
            #pragma unroll
            for (int c = 0; c < 4; ++c)
                acc[r][c] = __builtin_amdgcn_mfma_i32_16x16x64_i8(
                    afrag[r], bfrag[c], acc[r][c], 0, 0, 0);
        // write next chunk into the other buffer (safe: it was last read in
        // iteration ks-1, fenced by that iteration's barrier)
        if (ks < NKS - 1) *(uint32_t*)(&Abuf[cur ^ 1][swr]) = pack01(nv);
        __syncthreads();
    }

    // Epilogue: C/D lane mapping col=l&15, row=(l>>4)*4+j (verified r5).
    float ps[4][4] = {};
    #pragma unroll
    for (int c = 0; c < 4; ++c) {
        const int col = w * 64 + c * 16 + cl;
        const float iv = invs[col];
        const float bf = b_ft[col];
        const float wo0 = W_out[col];
        const float wo1 = W_out[FT + col];
        #pragma unroll
        for (int r = 0; r < 4; ++r) {
            const float wo = (r < 2) ? wo0 : wo1;   // rows 0-31 stm, 32-63 nstm
            #pragma unroll
            for (int j = 0; j < 4; ++j) {
                float h = fmaf((float)acc[r][c][j], iv, bf);
                h = fminf(fmaxf(h, 0.0f), 1.0f);
                ps[r][j] = fmaf(h * h, wo, ps[r][j]);
            }
        }
    }
    #pragma unroll
    for (int r = 0; r < 4; ++r)
        #pragma unroll
        for (int j = 0; j < 4; ++j) {
            float v = ps[r][j];
            v += __shfl_xor(v, 1, 64);
            v += __shfl_xor(v, 2, 64);
            v += __shfl_xor(v, 4, 64);
            v += __shfl_xor(v, 8, 64);
            if (cl == 0) red[16 * r + 4 * q + j][w] = v;
        }
    __syncthreads();

    if (t < RB) {
        float x = b_out[0];
        #pragma unroll
        for (int w2 = 0; w2 < NW; ++w2)
            x += red[t][w2] + red[RB + t][w2];
        out[b0 + t] = 1.0f / (1.0f + expf(-x));
    }
}

extern "C" void kernel_launch(void* const* d_in, const int* in_sizes, int n_in,
                              void* d_out, int out_size, void* d_ws, size_t ws_size,
                              hipStream_t stream) {
    const float* board_stm  = (const float*)d_in[0];
    const float* board_nstm = (const float*)d_in[1];
    const float* W_ft       = (const float*)d_in[2];
    const float* b_ft       = (const float*)d_in[3];
    const float* W_out      = (const float*)d_in[4];
    const float* b_out      = (const float*)d_in[5];
    float* out = (float*)d_out;

    char* Wq = (char*)d_ws;                                // FT*NF i8 = 768 KB
    float* invs = (float*)((char*)d_ws + (size_t)FT * NF); // 4 KB

    prep_wq<<<FT, 192, 0, stream>>>(W_ft, Wq, invs);
    nnue_mfma<<<BATCH / RB, THREADS, 0, stream>>>(board_stm, board_nstm, Wq, invs,
                                                  b_ft, W_out, b_out, out);
}